// Round 4
// baseline (27275.201 us; speedup 1.0000x reference)
//
#include <hip/hip_runtime.h>
#include <cmath>

// Problem constants
#define NTAG    12
#define TAG_START 10
#define TAG_STOP  11
#define NEGV    (-10000.0f)

typedef unsigned int uint32;
typedef unsigned short u16;
typedef _Float16 f16x2 __attribute__((ext_vector_type(2)));

#if defined(__has_builtin)
# if __has_builtin(__builtin_amdgcn_fdot2)
#  define HAVE_FDOT2 1
# endif
#endif

#ifdef HAVE_FDOT2
#define FDOT2(a, b, c) __builtin_amdgcn_fdot2((a), (b), (c), false)
#else
#define FDOT2(a, b, c) ((c) + (float)(a)[0] * (float)(b)[0] + (float)(a)[1] * (float)(b)[1])
#endif

// bf16 <-> f32 helpers
__device__ inline float b2f(u16 h) {
    union { uint32 u; float f; } v; v.u = ((uint32)h) << 16; return v.f;
}
__device__ inline u16 f2b(float f) {
    union { float f; uint32 u; } v; v.f = f;
    uint32 u = v.u;
    uint32 r = (u + 0x7FFFu + ((u >> 16) & 1u)) >> 16;
    return (u16)r;
}
__device__ inline float flo(uint32 u) {
    union { uint32 u; float f; } v; v.u = u << 16; return v.f;
}
__device__ inline float fhi(uint32 u) {
    union { uint32 u; float f; } v; v.u = u & 0xFFFF0000u; return v.f;
}
__device__ inline f16x2 u2h(uint32 u) {
    union { uint32 u; f16x2 h; } v; v.u = u; return v.h;
}
__device__ inline uint32 packh(float a, float b) {
    union { _Float16 h[2]; uint32 u; } v;
    v.h[0] = (_Float16)a; v.h[1] = (_Float16)b; return v.u;
}

// ---------------------------------------------------------------------------
// ws layout (bytes):
//   Wps  u32 [2 dir][4 slice][256 jp][512 g_local]   4,194,304
//   Ft   f32 [32768][12]                             1,572,864
//   hg   u32 [2 par][2 dir][64 b][64... =2*128*256*4]  262,144
//   ctr  u32 [64 groups][16]                             4,096
//   Lout bf16 [32768][1024]                         67,108,864
//   Gx   bf16 [NB*512][4096]                     NB*4,194,304
// NB=64 -> ~341.5 MB (fit confirmed by round-2 layout of 345.5 MB running)
// ---------------------------------------------------------------------------

// --- Kernel 1: per-slice f16 K-pair repack of W_hh --------------------------
// Wps[((dir*4+slice)*256+jp)*512 + g_local], g_local = type*128 + u_l,
// source row g = type*512 + slice*128 + u_l.
__global__ __launch_bounds__(256) void k_pack(const float* __restrict__ Wf,
                                              const float* __restrict__ Wb,
                                              uint32* __restrict__ Wps) {
    int e = blockIdx.x;                 // 0..2047
    int dir = e >> 10, slice = (e >> 8) & 3, jp = e & 255;
    const float* W = dir ? Wb : Wf;     // [2048][512]
    uint32* out = Wps + ((size_t)((dir * 4 + slice) * 256 + jp)) * 512;
    for (int g = threadIdx.x; g < 512; g += 256) {
        int row = (g >> 7) * 512 + slice * 128 + (g & 127);
        float a = W[(size_t)row * 512 + 2 * jp];
        float b = W[(size_t)row * 512 + 2 * jp + 1];
        out[g] = packh(a, b);
    }
}

// --- Kernel 2: fused gather + input GEMM (unchanged) ------------------------
__global__ __launch_bounds__(256) void k_gemm(const int* __restrict__ sent,
        const float* __restrict__ emb,
        const float* __restrict__ Wf, const float* __restrict__ Wb,
        const float* __restrict__ bf, const float* __restrict__ bb,
        u16* __restrict__ Gxc, int b0c) {
    __shared__ __align__(16) float As[8][128];
    __shared__ __align__(16) float Bs[8][128];
    int bid = blockIdx.x;
    int nb = bid & 31;
    int mb = bid >> 5;
    int M0 = mb << 7, N0 = nb << 7;
    int t  = threadIdx.x;
    int tx = t & 15, ty = t >> 4;
    int lr = t >> 1;
    int lk = (t & 1) << 2;

    const float* wbase;
    const float* biasv;
    if (N0 < 2048) { wbase = Wf + (size_t)N0 * 512;          biasv = bf + N0; }
    else           { wbase = Wb + (size_t)(N0 - 2048) * 512; biasv = bb + (N0 - 2048); }

    float acc[8][8];
    #pragma unroll
    for (int i = 0; i < 8; ++i)
        #pragma unroll
        for (int j = 0; j < 8; ++j) acc[i][j] = 0.f;

    int sentv = sent[b0c * 512 + M0 + lr];
    const float* xrow = emb + (size_t)sentv * 512 + lk;
    const float* wrow = wbase + (size_t)lr * 512 + lk;

    for (int k0 = 0; k0 < 512; k0 += 8) {
        float4 av = *(const float4*)(xrow + k0);
        float4 bv = *(const float4*)(wrow + k0);
        As[lk + 0][lr] = av.x; As[lk + 1][lr] = av.y;
        As[lk + 2][lr] = av.z; As[lk + 3][lr] = av.w;
        Bs[lk + 0][lr] = bv.x; Bs[lk + 1][lr] = bv.y;
        Bs[lk + 2][lr] = bv.z; Bs[lk + 3][lr] = bv.w;
        __syncthreads();
        #pragma unroll
        for (int kk = 0; kk < 8; ++kk) {
            float a[8], b[8];
            *(float4*)(a)     = *(const float4*)&As[kk][ty << 3];
            *(float4*)(a + 4) = *(const float4*)&As[kk][(ty << 3) + 4];
            *(float4*)(b)     = *(const float4*)&Bs[kk][tx << 3];
            *(float4*)(b + 4) = *(const float4*)&Bs[kk][(tx << 3) + 4];
            #pragma unroll
            for (int i = 0; i < 8; ++i)
                #pragma unroll
                for (int j = 0; j < 8; ++j)
                    acc[i][j] = fmaf(a[i], b[j], acc[i][j]);
        }
        __syncthreads();
    }
    #pragma unroll
    for (int i = 0; i < 8; ++i) {
        size_t m = (size_t)M0 + (ty << 3) + i;
        float v[8];
        #pragma unroll
        for (int j = 0; j < 8; ++j) v[j] = acc[i][j] + biasv[(tx << 3) + j];
        uint4 pk;
        pk.x = (uint32)f2b(v[0]) | ((uint32)f2b(v[1]) << 16);
        pk.y = (uint32)f2b(v[2]) | ((uint32)f2b(v[3]) << 16);
        pk.z = (uint32)f2b(v[4]) | ((uint32)f2b(v[5]) << 16);
        pk.w = (uint32)f2b(v[6]) | ((uint32)f2b(v[7]) << 16);
        *(uint4*)(Gxc + m * 4096 + N0 + (tx << 3)) = pk;
    }
}

// --- Kernel 3: BiLSTM recurrence, 4-block groups per (batch-pair, dir) ------
// Each block owns a 128-unit slice (all 4 gate types). h exchanged through
// global hg (parity double-buffered) with a per-group monotonic counter.
__global__ __launch_bounds__(512) void k_lstm(const u16* __restrict__ Gxc,
        const uint32* __restrict__ Wps, u16* __restrict__ Lout,
        uint32* __restrict__ hg, uint32* __restrict__ ctr, int b0c) {
    int bid = blockIdx.x;
    int dir, pairL, slice, gid;
    if (gridDim.x == 256) {
        // same-XCD grouping (bid%8 -> XCD heuristic): group's 4 blocks share an XCD
        int xcd = bid & 7, k = bid >> 3;    // k: 0..31
        slice = k & 3;
        dir   = xcd >> 2;
        pairL = (xcd & 3) * 8 + (k >> 2);   // 0..31
        gid   = dir * 32 + pairL;
    } else {
        gid = bid >> 2; slice = bid & 3;
        dir = gid & 1;  pairL = gid >> 1;
    }
    int lb0 = pairL << 1;           // chunk-local batch base
    int b0  = b0c + lb0;            // global batch base

    __shared__ __align__(16) uint32   hsl[2][256];   // staged h (f16 pairs)
    __shared__ __align__(16) float    gb[2][512];    // gate preacts (g_local)
    __shared__ __align__(16) float    csl[2][128];   // cell state (own units)
    __shared__ __align__(16) _Float16 hnew[2][128];  // new h (own units)

    int t = threadIdx.x;
    if (t < 256) csl[t >> 7][t & 127] = 0.f;
    __syncthreads();

    int gq = t >> 2, jq = t & 3;            // gq: 0..127 (4 gates each), jq: j-range
    int type = gq >> 5, u4 = (gq & 31) << 2;
    int gxcol = (dir << 11) + (type << 9) + (slice << 7) + u4;
    const uint32* wblk = Wps + ((size_t)((dir * 4 + slice) * 256)) * 512 + (gq << 2);
    unsigned* myctr = (unsigned*)(ctr + gid * 16);

    for (int si = 0; si < 512; ++si) {
        int s = dir ? (511 - si) : si;

        // --- acquire: peers finished step si-1 ---
        if (si > 0) {
            if (t == 0) {
                unsigned target = (unsigned)(si << 2);
                while (atomicAdd(myctr, 0u) < target) __builtin_amdgcn_s_sleep(1);
            }
            __syncthreads();
            __threadfence();
            int bi = t >> 8, jp = t & 255;
            hsl[bi][jp] = hg[((size_t)((si & 1) * 128 + (dir << 6) + b0 + bi) << 8) + jp];
        } else {
            int bi = t >> 8, jp = t & 255;
            hsl[bi][jp] = 0u;
        }
        __syncthreads();

        // --- matvec: thread (gq, jq) does jp = 4*i+jq, gates 4gq..4gq+3 ---
        float a0, a1, a2, a3, a4, a5, a6, a7;
        if (jq == 0) {
            const u16* gx0 = Gxc + ((size_t)lb0 * 512 + s) * 4096 + gxcol;
            const u16* gx1 = gx0 + (size_t)512 * 4096;
            ushort4 q0 = *(const ushort4*)gx0;
            ushort4 q1 = *(const ushort4*)gx1;
            a0 = b2f(q0.x); a1 = b2f(q0.y); a2 = b2f(q0.z); a3 = b2f(q0.w);
            a4 = b2f(q1.x); a5 = b2f(q1.y); a6 = b2f(q1.z); a7 = b2f(q1.w);
        } else {
            a0 = a1 = a2 = a3 = a4 = a5 = a6 = a7 = 0.f;
        }
        const uint32* wp = wblk + (size_t)jq * 512;
        #pragma unroll 8
        for (int i = 0; i < 64; ++i) {
            uint4 wv = *(const uint4*)(wp + (size_t)(i << 2) * 512);
            int jp = (i << 2) + jq;
            f16x2 h0 = u2h(hsl[0][jp]);
            f16x2 h1 = u2h(hsl[1][jp]);
            f16x2 w0 = u2h(wv.x), w1 = u2h(wv.y), w2 = u2h(wv.z), w3 = u2h(wv.w);
            a0 = FDOT2(h0, w0, a0); a1 = FDOT2(h0, w1, a1);
            a2 = FDOT2(h0, w2, a2); a3 = FDOT2(h0, w3, a3);
            a4 = FDOT2(h1, w0, a4); a5 = FDOT2(h1, w1, a5);
            a6 = FDOT2(h1, w2, a6); a7 = FDOT2(h1, w3, a7);
        }
        // reduce across jq (lanes t^1, t^2)
        #pragma unroll
        for (int m = 1; m <= 2; m <<= 1) {
            a0 += __shfl_xor(a0, m); a1 += __shfl_xor(a1, m);
            a2 += __shfl_xor(a2, m); a3 += __shfl_xor(a3, m);
            a4 += __shfl_xor(a4, m); a5 += __shfl_xor(a5, m);
            a6 += __shfl_xor(a6, m); a7 += __shfl_xor(a7, m);
        }
        if (jq == 0) {
            *(float4*)&gb[0][u4 + (type << 7)] = make_float4(a0, a1, a2, a3);
            *(float4*)&gb[1][u4 + (type << 7)] = make_float4(a4, a5, a6, a7);
        }
        __syncthreads();

        // --- activation: t<256 -> (bi, unit) ---
        if (t < 256) {
            int bi = t >> 7, u = t & 127;
            float gi = gb[bi][u];
            float gf = gb[bi][128 + u];
            float gg = gb[bi][256 + u];
            float go = gb[bi][384 + u];
            float iv  = 1.f / (1.f + expf(-gi));
            float fvv = 1.f / (1.f + expf(-gf));
            float gv  = tanhf(gg);
            float ov  = 1.f / (1.f + expf(-go));
            float cn = fvv * csl[bi][u] + iv * gv;
            float hn = ov * tanhf(cn);
            csl[bi][u] = cn;
            hnew[bi][u] = (_Float16)hn;
            Lout[((size_t)(b0 + bi) * 512 + s) * 1024 + (dir << 9) + (slice << 7) + u] = f2b(hn);
        }
        __syncthreads();

        // --- publish h slice (parity buffer for step si+1) ---
        if (t < 128) {
            int bi = t >> 6, i = t & 63;
            uint32 two = packh((float)hnew[bi][2 * i], (float)hnew[bi][2 * i + 1]);
            hg[((size_t)(((si + 1) & 1) * 128 + (dir << 6) + b0 + bi) << 8) + (slice << 6) + i] = two;
        }
        __syncthreads();                 // drains vmcnt before barrier
        if (t == 0) {
            __threadfence();
            atomicAdd(myctr, 1u);
        }
    }
}

// --- Kernel 4: feats = Lout(bf16) @ W_out^T + b_out ------------------------
__global__ __launch_bounds__(256) void k_feats(const u16* __restrict__ Lout,
        const float* __restrict__ Wout, const float* __restrict__ bout,
        float* __restrict__ Ft) {
    __shared__ __align__(16) float Wl[12 * 1024];
    for (int i = threadIdx.x; i < 12 * 1024; i += 256) Wl[i] = Wout[i];
    __syncthreads();
    int wv = threadIdx.x >> 6, lane = threadIdx.x & 63;
    size_t row = (size_t)blockIdx.x * 4 + wv;
    const uint4* xr = (const uint4*)(Lout + row * 1024);
    float acc[12];
    #pragma unroll
    for (int tg = 0; tg < 12; ++tg) acc[tg] = 0.f;
    #pragma unroll
    for (int c = 0; c < 2; ++c) {
        int e8 = lane + (c << 6);
        uint4 xv = xr[e8];
        float x0 = flo(xv.x), x1 = fhi(xv.x);
        float x2 = flo(xv.y), x3 = fhi(xv.y);
        float x4 = flo(xv.z), x5 = fhi(xv.z);
        float x6 = flo(xv.w), x7 = fhi(xv.w);
        #pragma unroll
        for (int tg = 0; tg < 12; ++tg) {
            const float* wpt = &Wl[tg * 1024 + (e8 << 3)];
            float4 wa = *(const float4*)wpt;
            float4 wb = *(const float4*)(wpt + 4);
            acc[tg] += x0 * wa.x + x1 * wa.y + x2 * wa.z + x3 * wa.w
                     + x4 * wb.x + x5 * wb.y + x6 * wb.z + x7 * wb.w;
        }
    }
    #pragma unroll
    for (int tg = 0; tg < 12; ++tg) {
        #pragma unroll
        for (int off = 32; off > 0; off >>= 1)
            acc[tg] += __shfl_xor(acc[tg], off);
    }
    float v = 0.f;
    #pragma unroll
    for (int tg = 0; tg < 12; ++tg)
        if (lane == tg) v = acc[tg];
    if (lane < 12) Ft[row * 12 + lane] = v + bout[lane];
}

// --- Kernel 5: Viterbi per batch (1 wave). ---------------------------------
__global__ __launch_bounds__(64) void k_viterbi(const float* __restrict__ Ft,
        const float* __restrict__ trans, float* __restrict__ out) {
    int b = blockIdx.x;
    int lane = threadIdx.x;
    __shared__ unsigned char bps[512][12];
    float tr[12];
    #pragma unroll
    for (int p = 0; p < 12; ++p)
        tr[p] = (lane < 12) ? trans[lane * 12 + p] : 0.f;
    float fv = (lane == TAG_START) ? 0.f : NEGV;
    const float* fb = Ft + (size_t)b * 512 * 12;
    for (int s = 0; s < 512; ++s) {
        float m = -3.4e38f;
        int bp = 0;
        #pragma unroll
        for (int p = 0; p < 12; ++p) {
            float v = __shfl(fv, p) + tr[p];
            if (v > m) { m = v; bp = p; }
        }
        float feat = (lane < 12) ? fb[s * 12 + lane] : 0.f;
        fv = m + feat;
        if (lane < 12) bps[s][lane] = (unsigned char)bp;
    }
    float term = fv + ((lane < 12) ? trans[TAG_STOP * 12 + lane] : 0.f);
    __syncthreads();
    float best = -3.4e38f; int tag = 0;
    #pragma unroll
    for (int p = 0; p < 12; ++p) {
        float v = __shfl(term, p);
        if (v > best) { best = v; tag = p; }
    }
    if (lane == 0) {
        out[b] = best;
        int tg = tag;
        for (int s = 511; s >= 0; --s) {
            out[64 + (size_t)b * 512 + s] = (float)tg;
            tg = bps[s][tg];
        }
    }
}

extern "C" void kernel_launch(void* const* d_in, const int* in_sizes, int n_in,
                              void* d_out, int out_size, void* d_ws, size_t ws_size,
                              hipStream_t stream) {
    const int*   sent   = (const int*)  d_in[0];
    const float* emb    = (const float*)d_in[1];
    const float* W_ih_f = (const float*)d_in[2];
    const float* W_hh_f = (const float*)d_in[3];
    const float* b_f    = (const float*)d_in[4];
    const float* W_ih_b = (const float*)d_in[5];
    const float* W_hh_b = (const float*)d_in[6];
    const float* b_b    = (const float*)d_in[7];
    const float* W_out  = (const float*)d_in[8];
    const float* b_out  = (const float*)d_in[9];
    const float* trans  = (const float*)d_in[10];
    float* out = (float*)d_out;

    char* wsB = (char*)d_ws;
    size_t off = 0;
    uint32* Wps = (uint32*)(wsB + off); off += 4194304;
    float*  Ft  = (float*) (wsB + off); off += 1572864;
    uint32* hg  = (uint32*)(wsB + off); off += 262144;
    uint32* ctr = (uint32*)(wsB + off); off += 4096;
    u16*    Lout= (u16*)   (wsB + off); off += 67108864;
    size_t fixed = off;
    u16*    Gxc = (u16*)   (wsB + off);

    int NB = 64;
    while (NB > 2 && fixed + (size_t)NB * 4194304ull > ws_size) NB >>= 1;

    k_pack<<<2048, 256, 0, stream>>>(W_hh_f, W_hh_b, Wps);
    for (int c = 0; c < 64; c += NB) {
        hipMemsetAsync(ctr, 0, 4096, stream);
        k_gemm<<<NB * 128, 256, 0, stream>>>(sent, emb, W_ih_f, W_ih_b, b_f, b_b, Gxc, c);
        k_lstm<<<NB * 4, 512, 0, stream>>>(Gxc, Wps, Lout, hg, ctr, c);
    }
    k_feats  <<<8192, 256, 0, stream>>>(Lout, W_out, b_out, Ft);
    k_viterbi<<<64, 64, 0, stream>>>(Ft, trans, out);
}

// Round 5
// 6505.835 us; speedup vs baseline: 4.1924x; 4.1924x over previous
//
#include <hip/hip_runtime.h>
#include <cmath>

// Problem constants
#define NTAG    12
#define TAG_START 10
#define TAG_STOP  11
#define NEGV    (-10000.0f)

typedef unsigned int uint32;
typedef unsigned short u16;

#if defined(__has_builtin)
# if __has_builtin(__builtin_amdgcn_sdot4)
#  define HAVE_SDOT4 1
# endif
#endif

#ifdef HAVE_SDOT4
#define SDOT4(a, b, c) __builtin_amdgcn_sdot4((int)(a), (int)(b), (c), false)
#else
__device__ inline int sdot4_sw(uint32 a, uint32 b, int c) {
    int r = c;
    r += ((int)(a << 24) >> 24) * ((int)(b << 24) >> 24);
    r += ((int)(a << 16) >> 24) * ((int)(b << 16) >> 24);
    r += ((int)(a << 8)  >> 24) * ((int)(b << 8)  >> 24);
    r += ((int)a >> 24)         * ((int)b >> 24);
    return r;
}
#define SDOT4(a, b, c) sdot4_sw((a), (b), (c))
#endif

// bf16 <-> f32 helpers
__device__ inline float b2f(u16 h) {
    union { uint32 u; float f; } v; v.u = ((uint32)h) << 16; return v.f;
}
__device__ inline u16 f2b(float f) {
    union { float f; uint32 u; } v; v.f = f;
    uint32 u = v.u;
    uint32 r = (u + 0x7FFFu + ((u >> 16) & 1u)) >> 16;
    return (u16)r;
}
__device__ inline float flo(uint32 u) {
    union { uint32 u; float f; } v; v.u = u << 16; return v.f;
}
__device__ inline float fhi(uint32 u) {
    union { uint32 u; float f; } v; v.u = u & 0xFFFF0000u; return v.f;
}

// ---------------------------------------------------------------------------
// ws layout (bytes):
//   Wq   u32 [2 dir][128 jq][2048 g]   2,097,152   int8 K-quad packed W_hh^T
//   s127 f32 [2][2048]                    16,384   per-row scale / 127
//   Ft   f32 [32768][12]               1,572,864   feats
//   Lout bf16 [32768][1024]           67,108,864   bilstm output
//   Gx   bf16 [NB*512][4096]       NB*4,194,304    gate preacts (chunk)
// NB=64 -> ~339 MB (round-2/3 layout of ~342 MB ran fine)
// ---------------------------------------------------------------------------

// --- Kernel 1: int8 quantize+pack W_hh. One block (64 thr) per (dir, gate row).
// Wq[((dir*128)+jq)*2048 + g] = packed int8 quad {w[g][4jq..4jq+3] / s_g}.
__global__ __launch_bounds__(64) void k_pack(const float* __restrict__ Wf,
                                             const float* __restrict__ Wb,
                                             uint32* __restrict__ Wq,
                                             float* __restrict__ s127) {
    int e = blockIdx.x;                 // 0..4095
    int dir = e >> 11, g = e & 2047;
    const float* W = (dir ? Wb : Wf) + (size_t)g * 512;
    int t = threadIdx.x;
    float w[8];
    float m = 0.f;
    #pragma unroll
    for (int i = 0; i < 8; ++i) {
        w[i] = W[t * 8 + i];
        m = fmaxf(m, fabsf(w[i]));
    }
    #pragma unroll
    for (int off = 32; off > 0; off >>= 1)
        m = fmaxf(m, __shfl_xor(m, off));
    float s = (m > 0.f) ? (m / 127.f) : 1.f;
    float inv = 1.f / s;
    uint32 d0 = 0, d1 = 0;
    #pragma unroll
    for (int i = 0; i < 4; ++i) {
        uint32 q0 = (uint32)((int)rintf(w[i] * inv)) & 0xFFu;
        uint32 q1 = (uint32)((int)rintf(w[4 + i] * inv)) & 0xFFu;
        d0 |= q0 << (8 * i);
        d1 |= q1 << (8 * i);
    }
    Wq[((size_t)(dir * 128) + (t << 1)) * 2048 + g] = d0;
    Wq[((size_t)(dir * 128) + (t << 1) + 1) * 2048 + g] = d1;
    if (t == 0) s127[dir * 2048 + g] = s / 127.f;
}

// --- Kernel 2: fused gather + input GEMM (unchanged from round 3) -----------
__global__ __launch_bounds__(256) void k_gemm(const int* __restrict__ sent,
        const float* __restrict__ emb,
        const float* __restrict__ Wf, const float* __restrict__ Wb,
        const float* __restrict__ bf, const float* __restrict__ bb,
        u16* __restrict__ Gxc, int b0c) {
    __shared__ __align__(16) float As[8][128];
    __shared__ __align__(16) float Bs[8][128];
    int bid = blockIdx.x;
    int nb = bid & 31;
    int mb = bid >> 5;
    int M0 = mb << 7, N0 = nb << 7;
    int t  = threadIdx.x;
    int tx = t & 15, ty = t >> 4;
    int lr = t >> 1;
    int lk = (t & 1) << 2;

    const float* wbase;
    const float* biasv;
    if (N0 < 2048) { wbase = Wf + (size_t)N0 * 512;          biasv = bf + N0; }
    else           { wbase = Wb + (size_t)(N0 - 2048) * 512; biasv = bb + (N0 - 2048); }

    float acc[8][8];
    #pragma unroll
    for (int i = 0; i < 8; ++i)
        #pragma unroll
        for (int j = 0; j < 8; ++j) acc[i][j] = 0.f;

    int sentv = sent[b0c * 512 + M0 + lr];
    const float* xrow = emb + (size_t)sentv * 512 + lk;
    const float* wrow = wbase + (size_t)lr * 512 + lk;

    for (int k0 = 0; k0 < 512; k0 += 8) {
        float4 av = *(const float4*)(xrow + k0);
        float4 bv = *(const float4*)(wrow + k0);
        As[lk + 0][lr] = av.x; As[lk + 1][lr] = av.y;
        As[lk + 2][lr] = av.z; As[lk + 3][lr] = av.w;
        Bs[lk + 0][lr] = bv.x; Bs[lk + 1][lr] = bv.y;
        Bs[lk + 2][lr] = bv.z; Bs[lk + 3][lr] = bv.w;
        __syncthreads();
        #pragma unroll
        for (int kk = 0; kk < 8; ++kk) {
            float a[8], b[8];
            *(float4*)(a)     = *(const float4*)&As[kk][ty << 3];
            *(float4*)(a + 4) = *(const float4*)&As[kk][(ty << 3) + 4];
            *(float4*)(b)     = *(const float4*)&Bs[kk][tx << 3];
            *(float4*)(b + 4) = *(const float4*)&Bs[kk][(tx << 3) + 4];
            #pragma unroll
            for (int i = 0; i < 8; ++i)
                #pragma unroll
                for (int j = 0; j < 8; ++j)
                    acc[i][j] = fmaf(a[i], b[j], acc[i][j]);
        }
        __syncthreads();
    }
    #pragma unroll
    for (int i = 0; i < 8; ++i) {
        size_t m = (size_t)M0 + (ty << 3) + i;
        float v[8];
        #pragma unroll
        for (int j = 0; j < 8; ++j) v[j] = acc[i][j] + biasv[(tx << 3) + j];
        uint4 pk;
        pk.x = (uint32)f2b(v[0]) | ((uint32)f2b(v[1]) << 16);
        pk.y = (uint32)f2b(v[2]) | ((uint32)f2b(v[3]) << 16);
        pk.z = (uint32)f2b(v[4]) | ((uint32)f2b(v[5]) << 16);
        pk.w = (uint32)f2b(v[6]) | ((uint32)f2b(v[7]) << 16);
        *(uint4*)(Gxc + m * 4096 + N0 + (tx << 3)) = pk;
    }
}

// --- Kernel 3: BiLSTM recurrence, int8 weights + sdot4 ----------------------
// One block = (2 batches, 1 dir), self-contained (no inter-block sync).
// blockIdx%8 -> XCD; XCDs 0-3 dir0, 4-7 dir1: each XCD L2 caches 1MB Wq.
__global__ __launch_bounds__(512) void k_lstm(const u16* __restrict__ Gxc,
        const uint32* __restrict__ Wq, const float* __restrict__ s127,
        u16* __restrict__ Lout, int b0c) {
    int dir, slot;
    if (gridDim.x >= 8) {
        int xid = blockIdx.x & 7, q = blockIdx.x >> 3;
        dir  = xid >> 2;
        slot = (xid & 3) | (q << 2);
    } else {
        dir  = blockIdx.x & 1;
        slot = blockIdx.x >> 1;
    }
    int b0  = b0c + (slot << 1);
    int lb0 = slot << 1;

    __shared__ __align__(16) uint32 hq[2][128];   // i8-packed h (4 units/dword)
    __shared__ __align__(16) float  gb[2][2048];  // gate preacts
    __shared__ __align__(16) float  cs[2][512];   // cell state

    int t = threadIdx.x;
    if (t < 256) hq[t >> 7][t & 127] = 0u;
    cs[0][t] = 0.f; cs[1][t] = 0.f;
    __syncthreads();

    int g4 = t << 2;                    // 4 consecutive gates owned by thread
    const uint32* wp = Wq + (size_t)dir * (128 * 2048) + g4;
    float4 sc = *(const float4*)(s127 + dir * 2048 + g4);
    const u16* gxb0 = Gxc + (size_t)lb0 * 512 * 4096 + (dir << 11) + g4;
    const u16* gxb1 = gxb0 + (size_t)512 * 4096;

    for (int si = 0; si < 512; ++si) {
        int s = dir ? (511 - si) : si;
        ushort4 q0 = *(const ushort4*)(gxb0 + (size_t)s * 4096);
        ushort4 q1 = *(const ushort4*)(gxb1 + (size_t)s * 4096);

        int a00 = 0, a01 = 0, a02 = 0, a03 = 0;
        int a10 = 0, a11 = 0, a12 = 0, a13 = 0;
        #pragma unroll 8
        for (int jq = 0; jq < 128; ++jq) {
            uint4 wv = *(const uint4*)(wp + (size_t)jq * 2048);
            uint32 h0 = hq[0][jq];
            uint32 h1 = hq[1][jq];
            a00 = SDOT4(h0, wv.x, a00); a01 = SDOT4(h0, wv.y, a01);
            a02 = SDOT4(h0, wv.z, a02); a03 = SDOT4(h0, wv.w, a03);
            a10 = SDOT4(h1, wv.x, a10); a11 = SDOT4(h1, wv.y, a11);
            a12 = SDOT4(h1, wv.z, a12); a13 = SDOT4(h1, wv.w, a13);
        }
        float4 p0 = make_float4(b2f(q0.x) + sc.x * (float)a00,
                                b2f(q0.y) + sc.y * (float)a01,
                                b2f(q0.z) + sc.z * (float)a02,
                                b2f(q0.w) + sc.w * (float)a03);
        float4 p1 = make_float4(b2f(q1.x) + sc.x * (float)a10,
                                b2f(q1.y) + sc.y * (float)a11,
                                b2f(q1.z) + sc.z * (float)a12,
                                b2f(q1.w) + sc.w * (float)a13);
        *(float4*)&gb[0][g4] = p0;
        *(float4*)&gb[1][g4] = p1;
        __syncthreads();

        // activation: thread t = unit t, both batches
        #pragma unroll
        for (int bi = 0; bi < 2; ++bi) {
            float gi = gb[bi][t];
            float gf = gb[bi][512 + t];
            float gg = gb[bi][1024 + t];
            float go = gb[bi][1536 + t];
            float iv  = 1.f / (1.f + expf(-gi));
            float fvv = 1.f / (1.f + expf(-gf));
            float gv  = tanhf(gg);
            float ov  = 1.f / (1.f + expf(-go));
            float cn = fvv * cs[bi][t] + iv * gv;
            float hn = ov * tanhf(cn);
            cs[bi][t] = cn;
            ((signed char*)hq[bi])[t] = (signed char)(int)rintf(hn * 127.f);
            Lout[((size_t)(b0 + bi) * 512 + s) * 1024 + (dir << 9) + t] = f2b(hn);
        }
        __syncthreads();
    }
}

// --- Kernel 4: feats = Lout(bf16) @ W_out^T + b_out ------------------------
__global__ __launch_bounds__(256) void k_feats(const u16* __restrict__ Lout,
        const float* __restrict__ Wout, const float* __restrict__ bout,
        float* __restrict__ Ft) {
    __shared__ __align__(16) float Wl[12 * 1024];
    for (int i = threadIdx.x; i < 12 * 1024; i += 256) Wl[i] = Wout[i];
    __syncthreads();
    int wv = threadIdx.x >> 6, lane = threadIdx.x & 63;
    size_t row = (size_t)blockIdx.x * 4 + wv;
    const uint4* xr = (const uint4*)(Lout + row * 1024);
    float acc[12];
    #pragma unroll
    for (int tg = 0; tg < 12; ++tg) acc[tg] = 0.f;
    #pragma unroll
    for (int c = 0; c < 2; ++c) {
        int e8 = lane + (c << 6);
        uint4 xv = xr[e8];
        float x0 = flo(xv.x), x1 = fhi(xv.x);
        float x2 = flo(xv.y), x3 = fhi(xv.y);
        float x4 = flo(xv.z), x5 = fhi(xv.z);
        float x6 = flo(xv.w), x7 = fhi(xv.w);
        #pragma unroll
        for (int tg = 0; tg < 12; ++tg) {
            const float* wpt = &Wl[tg * 1024 + (e8 << 3)];
            float4 wa = *(const float4*)wpt;
            float4 wb = *(const float4*)(wpt + 4);
            acc[tg] += x0 * wa.x + x1 * wa.y + x2 * wa.z + x3 * wa.w
                     + x4 * wb.x + x5 * wb.y + x6 * wb.z + x7 * wb.w;
        }
    }
    #pragma unroll
    for (int tg = 0; tg < 12; ++tg) {
        #pragma unroll
        for (int off = 32; off > 0; off >>= 1)
            acc[tg] += __shfl_xor(acc[tg], off);
    }
    float v = 0.f;
    #pragma unroll
    for (int tg = 0; tg < 12; ++tg)
        if (lane == tg) v = acc[tg];
    if (lane < 12) Ft[row * 12 + lane] = v + bout[lane];
}

// --- Kernel 5: Viterbi per batch (1 wave). ---------------------------------
__global__ __launch_bounds__(64) void k_viterbi(const float* __restrict__ Ft,
        const float* __restrict__ trans, float* __restrict__ out) {
    int b = blockIdx.x;
    int lane = threadIdx.x;
    __shared__ unsigned char bps[512][12];
    float tr[12];
    #pragma unroll
    for (int p = 0; p < 12; ++p)
        tr[p] = (lane < 12) ? trans[lane * 12 + p] : 0.f;
    float fv = (lane == TAG_START) ? 0.f : NEGV;
    const float* fb = Ft + (size_t)b * 512 * 12;
    for (int s = 0; s < 512; ++s) {
        float m = -3.4e38f;
        int bp = 0;
        #pragma unroll
        for (int p = 0; p < 12; ++p) {
            float v = __shfl(fv, p) + tr[p];
            if (v > m) { m = v; bp = p; }
        }
        float feat = (lane < 12) ? fb[s * 12 + lane] : 0.f;
        fv = m + feat;
        if (lane < 12) bps[s][lane] = (unsigned char)bp;
    }
    float term = fv + ((lane < 12) ? trans[TAG_STOP * 12 + lane] : 0.f);
    __syncthreads();
    float best = -3.4e38f; int tag = 0;
    #pragma unroll
    for (int p = 0; p < 12; ++p) {
        float v = __shfl(term, p);
        if (v > best) { best = v; tag = p; }
    }
    if (lane == 0) {
        out[b] = best;
        int tg = tag;
        for (int s = 511; s >= 0; --s) {
            out[64 + (size_t)b * 512 + s] = (float)tg;
            tg = bps[s][tg];
        }
    }
}

extern "C" void kernel_launch(void* const* d_in, const int* in_sizes, int n_in,
                              void* d_out, int out_size, void* d_ws, size_t ws_size,
                              hipStream_t stream) {
    const int*   sent   = (const int*)  d_in[0];
    const float* emb    = (const float*)d_in[1];
    const float* W_ih_f = (const float*)d_in[2];
    const float* W_hh_f = (const float*)d_in[3];
    const float* b_f    = (const float*)d_in[4];
    const float* W_ih_b = (const float*)d_in[5];
    const float* W_hh_b = (const float*)d_in[6];
    const float* b_b    = (const float*)d_in[7];
    const float* W_out  = (const float*)d_in[8];
    const float* b_out  = (const float*)d_in[9];
    const float* trans  = (const float*)d_in[10];
    float* out = (float*)d_out;

    char* wsB = (char*)d_ws;
    size_t off = 0;
    uint32* Wq   = (uint32*)(wsB + off); off += 2097152;
    float*  s127 = (float*) (wsB + off); off += 16384;
    float*  Ft   = (float*) (wsB + off); off += 1572864;
    u16*    Lout = (u16*)   (wsB + off); off += 67108864;
    size_t fixed = off;
    u16*    Gxc  = (u16*)   (wsB + off);

    int NB = 64;
    while (NB > 2 && fixed + (size_t)NB * 4194304ull > ws_size) NB >>= 1;

    k_pack<<<4096, 64, 0, stream>>>(W_hh_f, W_hh_b, Wq, s127);
    for (int c = 0; c < 64; c += NB) {
        k_gemm<<<NB * 128, 256, 0, stream>>>(sent, emb, W_ih_f, W_ih_b, b_f, b_b, Gxc, c);
        k_lstm<<<NB * 4 / 4, 512, 0, stream>>>(Gxc, Wq, s127, Lout, c);
    }
    k_feats  <<<8192, 256, 0, stream>>>(Lout, W_out, b_out, Ft);
    k_viterbi<<<64, 64, 0, stream>>>(Ft, trans, out);
}

// Round 6
// 4933.899 us; speedup vs baseline: 5.5281x; 1.3186x over previous
//
#include <hip/hip_runtime.h>
#include <cmath>

// Problem constants
#define NTAG    12
#define TAG_START 10
#define TAG_STOP  11
#define NEGV    (-10000.0f)

typedef unsigned int uint32;
typedef unsigned short u16;
typedef __attribute__((ext_vector_type(8))) short bf16x8;
typedef __attribute__((ext_vector_type(4))) float f32x4;

#if defined(__has_builtin)
# if __has_builtin(__builtin_amdgcn_sdot4)
#  define HAVE_SDOT4 1
# endif
#endif

#ifdef HAVE_SDOT4
#define SDOT4(a, b, c) __builtin_amdgcn_sdot4((int)(a), (int)(b), (c), false)
#else
__device__ inline int sdot4_sw(uint32 a, uint32 b, int c) {
    int r = c;
    r += ((int)(a << 24) >> 24) * ((int)(b << 24) >> 24);
    r += ((int)(a << 16) >> 24) * ((int)(b << 16) >> 24);
    r += ((int)(a << 8)  >> 24) * ((int)(b << 8)  >> 24);
    r += ((int)a >> 24)         * ((int)b >> 24);
    return r;
}
#define SDOT4(a, b, c) sdot4_sw((a), (b), (c))
#endif

// bf16 <-> f32 helpers
__device__ inline float b2f(u16 h) {
    union { uint32 u; float f; } v; v.u = ((uint32)h) << 16; return v.f;
}
__device__ inline u16 f2b(float f) {
    union { float f; uint32 u; } v; v.f = f;
    uint32 u = v.u;
    uint32 r = (u + 0x7FFFu + ((u >> 16) & 1u)) >> 16;
    return (u16)r;
}
__device__ inline uint32 f2b2(float a, float b) {
    return (uint32)f2b(a) | ((uint32)f2b(b) << 16);
}
__device__ inline float flo(uint32 u) {
    union { uint32 u; float f; } v; v.u = u << 16; return v.f;
}
__device__ inline float fhi(uint32 u) {
    union { uint32 u; float f; } v; v.u = u & 0xFFFF0000u; return v.f;
}

// ---------------------------------------------------------------------------
// ws layout (bytes):
//   Wq      u32 [2 dir][128 jq][2048 g]   2,097,152   int8 K-quad W_hh^T
//   s127    f32 [2][2048]                    16,384   per-row scale / 127
//   Wihb    u16 [4096][512]               4,194,304   bf16 W_ih (f then b)
//   biascat f32 [4096]                       16,384   bias (f then b)
//   Ft      f32 [32768][12]               1,572,864   feats
//   Lout    bf16 [32768][1024]           67,108,864   bilstm output
//   Gx      bf16 [NB*512][4096]       NB*4,194,304    gate preacts (chunk)
// NB=64 -> ~343.5 MB (round-2's 345.5 MB ran fine)
// ---------------------------------------------------------------------------

// --- Kernel 0: pack W_ih + bias to bf16 concat -------------------------------
__global__ __launch_bounds__(256) void k_packw(const float* __restrict__ Wf,
        const float* __restrict__ Wb, const float* __restrict__ bf,
        const float* __restrict__ bb, u16* __restrict__ Wihb,
        float* __restrict__ biascat) {
    int g = blockIdx.x;           // 0..4095
    const float* src = (g < 2048) ? (Wf + (size_t)g * 512)
                                  : (Wb + (size_t)(g - 2048) * 512);
    for (int k = threadIdx.x; k < 512; k += 256)
        Wihb[(size_t)g * 512 + k] = f2b(src[k]);
    if (threadIdx.x == 0)
        biascat[g] = (g < 2048) ? bf[g] : bb[g - 2048];
}

// --- Kernel 1: int8 quantize+pack W_hh (unchanged from round 5) -------------
__global__ __launch_bounds__(64) void k_pack(const float* __restrict__ Wf,
                                             const float* __restrict__ Wb,
                                             uint32* __restrict__ Wq,
                                             float* __restrict__ s127) {
    int e = blockIdx.x;                 // 0..4095
    int dir = e >> 11, g = e & 2047;
    const float* W = (dir ? Wb : Wf) + (size_t)g * 512;
    int t = threadIdx.x;
    float w[8];
    float m = 0.f;
    #pragma unroll
    for (int i = 0; i < 8; ++i) {
        w[i] = W[t * 8 + i];
        m = fmaxf(m, fabsf(w[i]));
    }
    #pragma unroll
    for (int off = 32; off > 0; off >>= 1)
        m = fmaxf(m, __shfl_xor(m, off));
    float s = (m > 0.f) ? (m / 127.f) : 1.f;
    float inv = 1.f / s;
    uint32 d0 = 0, d1 = 0;
    #pragma unroll
    for (int i = 0; i < 4; ++i) {
        uint32 q0 = (uint32)((int)rintf(w[i] * inv)) & 0xFFu;
        uint32 q1 = (uint32)((int)rintf(w[4 + i] * inv)) & 0xFFu;
        d0 |= q0 << (8 * i);
        d1 |= q1 << (8 * i);
    }
    Wq[((size_t)(dir * 128) + (t << 1)) * 2048 + g] = d0;
    Wq[((size_t)(dir * 128) + (t << 1) + 1) * 2048 + g] = d1;
    if (t == 0) s127[dir * 2048 + g] = s / 127.f;
}

// --- Kernel 2: fused gather + input GEMM, bf16 MFMA --------------------------
// Gx[m][g] = emb[sent[m]][:] . Wihb[g][:] + biascat[g]   (bf16 out)
// 128x128 tile, BK=64, 4 waves (2x2), 64x64 per wave, mfma 16x16x32.
__global__ __launch_bounds__(256) void k_gemm(const int* __restrict__ sent,
        const float* __restrict__ emb, const u16* __restrict__ Wihb,
        const float* __restrict__ biascat, u16* __restrict__ Gxc, int b0c) {
    __shared__ __align__(16) u16 As[128][72];   // [row][k] +8 pad
    __shared__ __align__(16) u16 Bs[128][72];   // [col(g)][k] +8 pad
    __shared__ int ssent[128];

    int bid = blockIdx.x;
    int nb = bid & 31, mb = bid >> 5;
    int M0 = mb << 7, N0 = nb << 7;
    int t = threadIdx.x;
    int w = t >> 6, l = t & 63;
    int wr = w >> 1, wc = w & 1;

    if (t < 128) ssent[t] = sent[b0c * 512 + M0 + t];

    f32x4 zero = {0.f, 0.f, 0.f, 0.f};
    f32x4 acc[4][4];
    #pragma unroll
    for (int i = 0; i < 4; ++i)
        #pragma unroll
        for (int j = 0; j < 4; ++j) acc[i][j] = zero;

    int srow = t >> 3;            // 0..31
    int skc  = (t & 7) << 3;      // bf16 k-offset 0..56
    __syncthreads();              // ssent ready

    for (int k0 = 0; k0 < 512; k0 += 64) {
        // stage A (emb f32 -> bf16) and B (Wihb bf16 copy)
        #pragma unroll
        for (int i = 0; i < 4; ++i) {
            int r = srow + (i << 5);
            const float* srcA = emb + (size_t)ssent[r] * 512 + k0 + skc;
            float4 f0 = *(const float4*)srcA;
            float4 f1 = *(const float4*)(srcA + 4);
            uint4 pa;
            pa.x = f2b2(f0.x, f0.y); pa.y = f2b2(f0.z, f0.w);
            pa.z = f2b2(f1.x, f1.y); pa.w = f2b2(f1.z, f1.w);
            *(uint4*)&As[r][skc] = pa;
            uint4 pb = *(const uint4*)(Wihb + (size_t)(N0 + r) * 512 + k0 + skc);
            *(uint4*)&Bs[r][skc] = pb;
        }
        __syncthreads();
        int lrow = l & 15, lk = (l >> 4) << 3;
        #pragma unroll
        for (int kk = 0; kk < 64; kk += 32) {
            bf16x8 af[4], bfr[4];
            #pragma unroll
            for (int i = 0; i < 4; ++i)
                af[i] = *(const bf16x8*)&As[(wr << 6) + (i << 4) + lrow][kk + lk];
            #pragma unroll
            for (int j = 0; j < 4; ++j)
                bfr[j] = *(const bf16x8*)&Bs[(wc << 6) + (j << 4) + lrow][kk + lk];
            #pragma unroll
            for (int i = 0; i < 4; ++i)
                #pragma unroll
                for (int j = 0; j < 4; ++j)
                    acc[i][j] = __builtin_amdgcn_mfma_f32_16x16x32_bf16(
                        af[i], bfr[j], acc[i][j], 0, 0, 0);
        }
        __syncthreads();
    }

    // epilogue: C/D layout col=lane&15, row=(lane>>4)*4+reg
    int lrow = l & 15, lq = l >> 4;
    #pragma unroll
    for (int j = 0; j < 4; ++j) {
        int col = N0 + (wc << 6) + (j << 4) + lrow;
        float bv = biascat[col];
        #pragma unroll
        for (int i = 0; i < 4; ++i) {
            int rbase = M0 + (wr << 6) + (i << 4) + (lq << 2);
            #pragma unroll
            for (int r = 0; r < 4; ++r)
                Gxc[(size_t)(rbase + r) * 4096 + col] = f2b(acc[i][j][r] + bv);
        }
    }
}

// --- Kernel 3: BiLSTM recurrence, int8 weights + sdot4 (unchanged) ----------
__global__ __launch_bounds__(512) void k_lstm(const u16* __restrict__ Gxc,
        const uint32* __restrict__ Wq, const float* __restrict__ s127,
        u16* __restrict__ Lout, int b0c) {
    int dir, slot;
    if (gridDim.x >= 8) {
        int xid = blockIdx.x & 7, q = blockIdx.x >> 3;
        dir  = xid >> 2;
        slot = (xid & 3) | (q << 2);
    } else {
        dir  = blockIdx.x & 1;
        slot = blockIdx.x >> 1;
    }
    int b0  = b0c + (slot << 1);
    int lb0 = slot << 1;

    __shared__ __align__(16) uint32 hq[2][128];   // i8-packed h
    __shared__ __align__(16) float  gb[2][2048];  // gate preacts
    __shared__ __align__(16) float  cs[2][512];   // cell state

    int t = threadIdx.x;
    if (t < 256) hq[t >> 7][t & 127] = 0u;
    cs[0][t] = 0.f; cs[1][t] = 0.f;
    __syncthreads();

    int g4 = t << 2;
    const uint32* wp = Wq + (size_t)dir * (128 * 2048) + g4;
    float4 sc = *(const float4*)(s127 + dir * 2048 + g4);
    const u16* gxb0 = Gxc + (size_t)lb0 * 512 * 4096 + (dir << 11) + g4;
    const u16* gxb1 = gxb0 + (size_t)512 * 4096;

    for (int si = 0; si < 512; ++si) {
        int s = dir ? (511 - si) : si;
        ushort4 q0 = *(const ushort4*)(gxb0 + (size_t)s * 4096);
        ushort4 q1 = *(const ushort4*)(gxb1 + (size_t)s * 4096);

        int a00 = 0, a01 = 0, a02 = 0, a03 = 0;
        int a10 = 0, a11 = 0, a12 = 0, a13 = 0;
        #pragma unroll 8
        for (int jq = 0; jq < 128; ++jq) {
            uint4 wv = *(const uint4*)(wp + (size_t)jq * 2048);
            uint32 h0 = hq[0][jq];
            uint32 h1 = hq[1][jq];
            a00 = SDOT4(h0, wv.x, a00); a01 = SDOT4(h0, wv.y, a01);
            a02 = SDOT4(h0, wv.z, a02); a03 = SDOT4(h0, wv.w, a03);
            a10 = SDOT4(h1, wv.x, a10); a11 = SDOT4(h1, wv.y, a11);
            a12 = SDOT4(h1, wv.z, a12); a13 = SDOT4(h1, wv.w, a13);
        }
        float4 p0 = make_float4(b2f(q0.x) + sc.x * (float)a00,
                                b2f(q0.y) + sc.y * (float)a01,
                                b2f(q0.z) + sc.z * (float)a02,
                                b2f(q0.w) + sc.w * (float)a03);
        float4 p1 = make_float4(b2f(q1.x) + sc.x * (float)a10,
                                b2f(q1.y) + sc.y * (float)a11,
                                b2f(q1.z) + sc.z * (float)a12,
                                b2f(q1.w) + sc.w * (float)a13);
        *(float4*)&gb[0][g4] = p0;
        *(float4*)&gb[1][g4] = p1;
        __syncthreads();

        #pragma unroll
        for (int bi = 0; bi < 2; ++bi) {
            float gi = gb[bi][t];
            float gf = gb[bi][512 + t];
            float gg = gb[bi][1024 + t];
            float go = gb[bi][1536 + t];
            float iv  = 1.f / (1.f + expf(-gi));
            float fvv = 1.f / (1.f + expf(-gf));
            float gv  = tanhf(gg);
            float ov  = 1.f / (1.f + expf(-go));
            float cn = fvv * cs[bi][t] + iv * gv;
            float hn = ov * tanhf(cn);
            cs[bi][t] = cn;
            ((signed char*)hq[bi])[t] = (signed char)(int)rintf(hn * 127.f);
            Lout[((size_t)(b0 + bi) * 512 + s) * 1024 + (dir << 9) + t] = f2b(hn);
        }
        __syncthreads();
    }
}

// --- Kernel 4: feats = Lout(bf16) @ W_out^T + b_out ------------------------
__global__ __launch_bounds__(256) void k_feats(const u16* __restrict__ Lout,
        const float* __restrict__ Wout, const float* __restrict__ bout,
        float* __restrict__ Ft) {
    __shared__ __align__(16) float Wl[12 * 1024];
    for (int i = threadIdx.x; i < 12 * 1024; i += 256) Wl[i] = Wout[i];
    __syncthreads();
    int wv = threadIdx.x >> 6, lane = threadIdx.x & 63;
    size_t row = (size_t)blockIdx.x * 4 + wv;
    const uint4* xr = (const uint4*)(Lout + row * 1024);
    float acc[12];
    #pragma unroll
    for (int tg = 0; tg < 12; ++tg) acc[tg] = 0.f;
    #pragma unroll
    for (int c = 0; c < 2; ++c) {
        int e8 = lane + (c << 6);
        uint4 xv = xr[e8];
        float x0 = flo(xv.x), x1 = fhi(xv.x);
        float x2 = flo(xv.y), x3 = fhi(xv.y);
        float x4 = flo(xv.z), x5 = fhi(xv.z);
        float x6 = flo(xv.w), x7 = fhi(xv.w);
        #pragma unroll
        for (int tg = 0; tg < 12; ++tg) {
            const float* wpt = &Wl[tg * 1024 + (e8 << 3)];
            float4 wa = *(const float4*)wpt;
            float4 wb = *(const float4*)(wpt + 4);
            acc[tg] += x0 * wa.x + x1 * wa.y + x2 * wa.z + x3 * wa.w
                     + x4 * wb.x + x5 * wb.y + x6 * wb.z + x7 * wb.w;
        }
    }
    #pragma unroll
    for (int tg = 0; tg < 12; ++tg) {
        #pragma unroll
        for (int off = 32; off > 0; off >>= 1)
            acc[tg] += __shfl_xor(acc[tg], off);
    }
    float v = 0.f;
    #pragma unroll
    for (int tg = 0; tg < 12; ++tg)
        if (lane == tg) v = acc[tg];
    if (lane < 12) Ft[row * 12 + lane] = v + bout[lane];
}

// --- Kernel 5: Viterbi per batch (1 wave). ---------------------------------
__global__ __launch_bounds__(64) void k_viterbi(const float* __restrict__ Ft,
        const float* __restrict__ trans, float* __restrict__ out) {
    int b = blockIdx.x;
    int lane = threadIdx.x;
    __shared__ unsigned char bps[512][12];
    float tr[12];
    #pragma unroll
    for (int p = 0; p < 12; ++p)
        tr[p] = (lane < 12) ? trans[lane * 12 + p] : 0.f;
    float fv = (lane == TAG_START) ? 0.f : NEGV;
    const float* fb = Ft + (size_t)b * 512 * 12;
    for (int s = 0; s < 512; ++s) {
        float m = -3.4e38f;
        int bp = 0;
        #pragma unroll
        for (int p = 0; p < 12; ++p) {
            float v = __shfl(fv, p) + tr[p];
            if (v > m) { m = v; bp = p; }
        }
        float feat = (lane < 12) ? fb[s * 12 + lane] : 0.f;
        fv = m + feat;
        if (lane < 12) bps[s][lane] = (unsigned char)bp;
    }
    float term = fv + ((lane < 12) ? trans[TAG_STOP * 12 + lane] : 0.f);
    __syncthreads();
    float best = -3.4e38f; int tag = 0;
    #pragma unroll
    for (int p = 0; p < 12; ++p) {
        float v = __shfl(term, p);
        if (v > best) { best = v; tag = p; }
    }
    if (lane == 0) {
        out[b] = best;
        int tg = tag;
        for (int s = 511; s >= 0; --s) {
            out[64 + (size_t)b * 512 + s] = (float)tg;
            tg = bps[s][tg];
        }
    }
}

extern "C" void kernel_launch(void* const* d_in, const int* in_sizes, int n_in,
                              void* d_out, int out_size, void* d_ws, size_t ws_size,
                              hipStream_t stream) {
    const int*   sent   = (const int*)  d_in[0];
    const float* emb    = (const float*)d_in[1];
    const float* W_ih_f = (const float*)d_in[2];
    const float* W_hh_f = (const float*)d_in[3];
    const float* b_f    = (const float*)d_in[4];
    const float* W_ih_b = (const float*)d_in[5];
    const float* W_hh_b = (const float*)d_in[6];
    const float* b_b    = (const float*)d_in[7];
    const float* W_out  = (const float*)d_in[8];
    const float* b_out  = (const float*)d_in[9];
    const float* trans  = (const float*)d_in[10];
    float* out = (float*)d_out;

    char* wsB = (char*)d_ws;
    size_t off = 0;
    uint32* Wq     = (uint32*)(wsB + off); off += 2097152;
    float*  s127   = (float*) (wsB + off); off += 16384;
    u16*    Wihb   = (u16*)   (wsB + off); off += 4194304;
    float*  biascat= (float*) (wsB + off); off += 16384;
    float*  Ft     = (float*) (wsB + off); off += 1572864;
    u16*    Lout   = (u16*)   (wsB + off); off += 67108864;
    size_t fixed = off;
    u16*    Gxc    = (u16*)   (wsB + off);

    int NB = 64;
    while (NB > 2 && fixed + (size_t)NB * 4194304ull > ws_size) NB >>= 1;

    k_packw<<<4096, 256, 0, stream>>>(W_ih_f, W_ih_b, b_f, b_b, Wihb, biascat);
    k_pack <<<4096, 64, 0, stream>>>(W_hh_f, W_hh_b, Wq, s127);
    for (int c = 0; c < 64; c += NB) {
        k_gemm<<<NB * 128, 256, 0, stream>>>(sent, emb, Wihb, biascat, Gxc, c);
        k_lstm<<<NB, 512, 0, stream>>>(Gxc, Wq, s127, Lout, c);
    }
    k_feats  <<<8192, 256, 0, stream>>>(Lout, W_out, b_out, Ft);
    k_viterbi<<<64, 64, 0, stream>>>(Ft, trans, out);
}

// Round 7
// 4277.023 us; speedup vs baseline: 6.3771x; 1.1536x over previous
//
#include <hip/hip_runtime.h>
#include <cmath>

// Problem constants
#define NTAG    12
#define TAG_START 10
#define TAG_STOP  11
#define NEGV    (-10000.0f)

// k_lstm weight residency split (of 128 j-quads)
#define JREG 40
#define JLDS 12
#define JSTR (128 - JREG - JLDS)   // 76

typedef unsigned int uint32;
typedef unsigned short u16;
typedef __attribute__((ext_vector_type(8))) short bf16x8;
typedef __attribute__((ext_vector_type(4))) float f32x4;

#if defined(__has_builtin)
# if __has_builtin(__builtin_amdgcn_sdot4)
#  define HAVE_SDOT4 1
# endif
#endif

#ifdef HAVE_SDOT4
#define SDOT4(a, b, c) __builtin_amdgcn_sdot4((int)(a), (int)(b), (c), false)
#else
__device__ inline int sdot4_sw(uint32 a, uint32 b, int c) {
    int r = c;
    r += ((int)(a << 24) >> 24) * ((int)(b << 24) >> 24);
    r += ((int)(a << 16) >> 24) * ((int)(b << 16) >> 24);
    r += ((int)(a << 8)  >> 24) * ((int)(b << 8)  >> 24);
    r += ((int)a >> 24)         * ((int)b >> 24);
    return r;
}
#define SDOT4(a, b, c) sdot4_sw((a), (b), (c))
#endif

// bf16 <-> f32 helpers
__device__ inline float b2f(u16 h) {
    union { uint32 u; float f; } v; v.u = ((uint32)h) << 16; return v.f;
}
__device__ inline u16 f2b(float f) {
    union { float f; uint32 u; } v; v.f = f;
    uint32 u = v.u;
    uint32 r = (u + 0x7FFFu + ((u >> 16) & 1u)) >> 16;
    return (u16)r;
}
__device__ inline uint32 f2b2(float a, float b) {
    return (uint32)f2b(a) | ((uint32)f2b(b) << 16);
}
__device__ inline float flo(uint32 u) {
    union { uint32 u; float f; } v; v.u = u << 16; return v.f;
}
__device__ inline float fhi(uint32 u) {
    union { uint32 u; float f; } v; v.u = u & 0xFFFF0000u; return v.f;
}

// ---------------------------------------------------------------------------
// ws layout (bytes):
//   Wq      u32 [2 dir][128 jq][2048 g]   2,097,152   int8 K-quad W_hh^T
//   s127    f32 [2][2048]                    16,384   per-row scale / 127
//   Wihb    u16 [4096][512]               4,194,304   bf16 W_ih (f then b)
//   biascat f32 [4096]                       16,384   bias (f then b)
//   Ft      f32 [32768][12]               1,572,864   feats
//   Lout    bf16 [32768][1024]           67,108,864   bilstm output
//   Gx      bf16 [NB*512][4096]       NB*4,194,304    gate preacts (chunk)
// ---------------------------------------------------------------------------

// --- Kernel 0: pack W_ih + bias to bf16 concat -------------------------------
__global__ __launch_bounds__(256) void k_packw(const float* __restrict__ Wf,
        const float* __restrict__ Wb, const float* __restrict__ bf,
        const float* __restrict__ bb, u16* __restrict__ Wihb,
        float* __restrict__ biascat) {
    int g = blockIdx.x;           // 0..4095
    const float* src = (g < 2048) ? (Wf + (size_t)g * 512)
                                  : (Wb + (size_t)(g - 2048) * 512);
    for (int k = threadIdx.x; k < 512; k += 256)
        Wihb[(size_t)g * 512 + k] = f2b(src[k]);
    if (threadIdx.x == 0)
        biascat[g] = (g < 2048) ? bf[g] : bb[g - 2048];
}

// --- Kernel 1: int8 quantize+pack W_hh ---------------------------------------
__global__ __launch_bounds__(64) void k_pack(const float* __restrict__ Wf,
                                             const float* __restrict__ Wb,
                                             uint32* __restrict__ Wq,
                                             float* __restrict__ s127) {
    int e = blockIdx.x;                 // 0..4095
    int dir = e >> 11, g = e & 2047;
    const float* W = (dir ? Wb : Wf) + (size_t)g * 512;
    int t = threadIdx.x;
    float w[8];
    float m = 0.f;
    #pragma unroll
    for (int i = 0; i < 8; ++i) {
        w[i] = W[t * 8 + i];
        m = fmaxf(m, fabsf(w[i]));
    }
    #pragma unroll
    for (int off = 32; off > 0; off >>= 1)
        m = fmaxf(m, __shfl_xor(m, off));
    float s = (m > 0.f) ? (m / 127.f) : 1.f;
    float inv = 1.f / s;
    uint32 d0 = 0, d1 = 0;
    #pragma unroll
    for (int i = 0; i < 4; ++i) {
        uint32 q0 = (uint32)((int)rintf(w[i] * inv)) & 0xFFu;
        uint32 q1 = (uint32)((int)rintf(w[4 + i] * inv)) & 0xFFu;
        d0 |= q0 << (8 * i);
        d1 |= q1 << (8 * i);
    }
    Wq[((size_t)(dir * 128) + (t << 1)) * 2048 + g] = d0;
    Wq[((size_t)(dir * 128) + (t << 1) + 1) * 2048 + g] = d1;
    if (t == 0) s127[dir * 2048 + g] = s / 127.f;
}

// --- Kernel 2: fused gather + input GEMM, bf16 MFMA (unchanged r6) ----------
__global__ __launch_bounds__(256) void k_gemm(const int* __restrict__ sent,
        const float* __restrict__ emb, const u16* __restrict__ Wihb,
        const float* __restrict__ biascat, u16* __restrict__ Gxc, int b0c) {
    __shared__ __align__(16) u16 As[128][72];
    __shared__ __align__(16) u16 Bs[128][72];
    __shared__ int ssent[128];

    int bid = blockIdx.x;
    int nb = bid & 31, mb = bid >> 5;
    int M0 = mb << 7, N0 = nb << 7;
    int t = threadIdx.x;
    int w = t >> 6, l = t & 63;
    int wr = w >> 1, wc = w & 1;

    if (t < 128) ssent[t] = sent[b0c * 512 + M0 + t];

    f32x4 zero = {0.f, 0.f, 0.f, 0.f};
    f32x4 acc[4][4];
    #pragma unroll
    for (int i = 0; i < 4; ++i)
        #pragma unroll
        for (int j = 0; j < 4; ++j) acc[i][j] = zero;

    int srow = t >> 3;
    int skc  = (t & 7) << 3;
    __syncthreads();

    for (int k0 = 0; k0 < 512; k0 += 64) {
        #pragma unroll
        for (int i = 0; i < 4; ++i) {
            int r = srow + (i << 5);
            const float* srcA = emb + (size_t)ssent[r] * 512 + k0 + skc;
            float4 f0 = *(const float4*)srcA;
            float4 f1 = *(const float4*)(srcA + 4);
            uint4 pa;
            pa.x = f2b2(f0.x, f0.y); pa.y = f2b2(f0.z, f0.w);
            pa.z = f2b2(f1.x, f1.y); pa.w = f2b2(f1.z, f1.w);
            *(uint4*)&As[r][skc] = pa;
            uint4 pb = *(const uint4*)(Wihb + (size_t)(N0 + r) * 512 + k0 + skc);
            *(uint4*)&Bs[r][skc] = pb;
        }
        __syncthreads();
        int lrow = l & 15, lk = (l >> 4) << 3;
        #pragma unroll
        for (int kk = 0; kk < 64; kk += 32) {
            bf16x8 af[4], bfr[4];
            #pragma unroll
            for (int i = 0; i < 4; ++i)
                af[i] = *(const bf16x8*)&As[(wr << 6) + (i << 4) + lrow][kk + lk];
            #pragma unroll
            for (int j = 0; j < 4; ++j)
                bfr[j] = *(const bf16x8*)&Bs[(wc << 6) + (j << 4) + lrow][kk + lk];
            #pragma unroll
            for (int i = 0; i < 4; ++i)
                #pragma unroll
                for (int j = 0; j < 4; ++j)
                    acc[i][j] = __builtin_amdgcn_mfma_f32_16x16x32_bf16(
                        af[i], bfr[j], acc[i][j], 0, 0, 0);
        }
        __syncthreads();
    }

    int lrow = l & 15, lq = l >> 4;
    #pragma unroll
    for (int j = 0; j < 4; ++j) {
        int col = N0 + (wc << 6) + (j << 4) + lrow;
        float bv = biascat[col];
        #pragma unroll
        for (int i = 0; i < 4; ++i) {
            int rbase = M0 + (wr << 6) + (i << 4) + (lq << 2);
            #pragma unroll
            for (int r = 0; r < 4; ++r)
                Gxc[(size_t)(rbase + r) * 4096 + col] = f2b(acc[i][j][r] + bv);
        }
    }
}

// --- Kernel 3: BiLSTM recurrence, 3-tier resident int8 weights + sdot4 ------
// One block = (2 batches, 1 dir). jq 0..JREG-1 in VGPRs, next JLDS in LDS,
// rest streamed from L2. blockIdx%8 -> XCD heuristic as before.
__global__ __launch_bounds__(512, 2) void k_lstm(const u16* __restrict__ Gxc,
        const uint32* __restrict__ Wq, const float* __restrict__ s127,
        u16* __restrict__ Lout, int b0c) {
    int dir, slot;
    if (gridDim.x >= 8) {
        int xid = blockIdx.x & 7, q = blockIdx.x >> 3;
        dir  = xid >> 2;
        slot = (xid & 3) | (q << 2);
    } else {
        dir  = blockIdx.x & 1;
        slot = blockIdx.x >> 1;
    }
    int b0  = b0c + (slot << 1);
    int lb0 = slot << 1;

    __shared__ __align__(16) uint32 wlds[JLDS][2048]; // 96 KB LDS-resident weights
    __shared__ __align__(16) uint32 hq[2][128];       // i8-packed h
    __shared__ __align__(16) float  gb[2][2048];      // gate preacts

    int t = threadIdx.x;
    if (t < 256) hq[t >> 7][t & 127] = 0u;
    float csr0 = 0.f, csr1 = 0.f;                     // cell state (unit t)

    const uint32* wsrc = Wq + (size_t)dir * (128 * 2048);
    // preload LDS tier (coalesced uint4 copy)
    {
        const uint4* src = (const uint4*)(wsrc + (size_t)JREG * 2048);
        uint4* dst = (uint4*)wlds;
        #pragma unroll
        for (int i = 0; i < JLDS; ++i)
            dst[t + i * 512] = src[t + i * 512];
    }
    // preload VGPR tier (static index only — stays in registers)
    int g4 = t << 2;
    const uint32* wp = wsrc + g4;
    uint4 wreg[JREG];
    #pragma unroll
    for (int i = 0; i < JREG; ++i)
        wreg[i] = *(const uint4*)(wp + (size_t)i * 2048);

    float4 sc = *(const float4*)(s127 + dir * 2048 + g4);
    const u16* gxb0 = Gxc + (size_t)lb0 * 512 * 4096 + (dir << 11) + g4;
    const u16* gxb1 = gxb0 + (size_t)512 * 4096;
    const uint32* spB = wsrc + (size_t)(JREG + JLDS) * 2048 + g4;
    __syncthreads();

    for (int si = 0; si < 512; ++si) {
        int s = dir ? (511 - si) : si;
        ushort4 q0 = *(const ushort4*)(gxb0 + (size_t)s * 4096);
        ushort4 q1 = *(const ushort4*)(gxb1 + (size_t)s * 4096);

        int a00 = 0, a01 = 0, a02 = 0, a03 = 0;
        int a10 = 0, a11 = 0, a12 = 0, a13 = 0;

        // tier 1: VGPR-resident (fully unrolled, static indices)
        #pragma unroll
        for (int i = 0; i < JREG; ++i) {
            uint4 wv = wreg[i];
            uint32 h0 = hq[0][i];
            uint32 h1 = hq[1][i];
            a00 = SDOT4(h0, wv.x, a00); a01 = SDOT4(h0, wv.y, a01);
            a02 = SDOT4(h0, wv.z, a02); a03 = SDOT4(h0, wv.w, a03);
            a10 = SDOT4(h1, wv.x, a10); a11 = SDOT4(h1, wv.y, a11);
            a12 = SDOT4(h1, wv.z, a12); a13 = SDOT4(h1, wv.w, a13);
        }
        // tier 2: LDS-resident
        #pragma unroll
        for (int i = 0; i < JLDS; ++i) {
            uint4 wv = *(const uint4*)&wlds[i][g4];
            uint32 h0 = hq[0][JREG + i];
            uint32 h1 = hq[1][JREG + i];
            a00 = SDOT4(h0, wv.x, a00); a01 = SDOT4(h0, wv.y, a01);
            a02 = SDOT4(h0, wv.z, a02); a03 = SDOT4(h0, wv.w, a03);
            a10 = SDOT4(h1, wv.x, a10); a11 = SDOT4(h1, wv.y, a11);
            a12 = SDOT4(h1, wv.z, a12); a13 = SDOT4(h1, wv.w, a13);
        }
        // tier 3: streamed from L2
        #pragma unroll 4
        for (int i = 0; i < JSTR; ++i) {
            uint4 wv = *(const uint4*)(spB + (size_t)i * 2048);
            uint32 h0 = hq[0][JREG + JLDS + i];
            uint32 h1 = hq[1][JREG + JLDS + i];
            a00 = SDOT4(h0, wv.x, a00); a01 = SDOT4(h0, wv.y, a01);
            a02 = SDOT4(h0, wv.z, a02); a03 = SDOT4(h0, wv.w, a03);
            a10 = SDOT4(h1, wv.x, a10); a11 = SDOT4(h1, wv.y, a11);
            a12 = SDOT4(h1, wv.z, a12); a13 = SDOT4(h1, wv.w, a13);
        }

        float4 p0 = make_float4(b2f(q0.x) + sc.x * (float)a00,
                                b2f(q0.y) + sc.y * (float)a01,
                                b2f(q0.z) + sc.z * (float)a02,
                                b2f(q0.w) + sc.w * (float)a03);
        float4 p1 = make_float4(b2f(q1.x) + sc.x * (float)a10,
                                b2f(q1.y) + sc.y * (float)a11,
                                b2f(q1.z) + sc.z * (float)a12,
                                b2f(q1.w) + sc.w * (float)a13);
        *(float4*)&gb[0][g4] = p0;
        *(float4*)&gb[1][g4] = p1;
        __syncthreads();

        // activation: thread t = unit t, both batches; c in registers
        {
            float gi = gb[0][t];
            float gf = gb[0][512 + t];
            float gg = gb[0][1024 + t];
            float go = gb[0][1536 + t];
            float iv  = 1.f / (1.f + expf(-gi));
            float fvv = 1.f / (1.f + expf(-gf));
            float gv  = tanhf(gg);
            float ov  = 1.f / (1.f + expf(-go));
            float cn = fvv * csr0 + iv * gv;
            float hn = ov * tanhf(cn);
            csr0 = cn;
            ((signed char*)hq[0])[t] = (signed char)(int)rintf(hn * 127.f);
            Lout[((size_t)(b0 + 0) * 512 + s) * 1024 + (dir << 9) + t] = f2b(hn);
        }
        {
            float gi = gb[1][t];
            float gf = gb[1][512 + t];
            float gg = gb[1][1024 + t];
            float go = gb[1][1536 + t];
            float iv  = 1.f / (1.f + expf(-gi));
            float fvv = 1.f / (1.f + expf(-gf));
            float gv  = tanhf(gg);
            float ov  = 1.f / (1.f + expf(-go));
            float cn = fvv * csr1 + iv * gv;
            float hn = ov * tanhf(cn);
            csr1 = cn;
            ((signed char*)hq[1])[t] = (signed char)(int)rintf(hn * 127.f);
            Lout[((size_t)(b0 + 1) * 512 + s) * 1024 + (dir << 9) + t] = f2b(hn);
        }
        __syncthreads();
    }
}

// --- Kernel 4: feats = Lout(bf16) @ W_out^T + b_out ------------------------
__global__ __launch_bounds__(256) void k_feats(const u16* __restrict__ Lout,
        const float* __restrict__ Wout, const float* __restrict__ bout,
        float* __restrict__ Ft) {
    __shared__ __align__(16) float Wl[12 * 1024];
    for (int i = threadIdx.x; i < 12 * 1024; i += 256) Wl[i] = Wout[i];
    __syncthreads();
    int wv = threadIdx.x >> 6, lane = threadIdx.x & 63;
    size_t row = (size_t)blockIdx.x * 4 + wv;
    const uint4* xr = (const uint4*)(Lout + row * 1024);
    float acc[12];
    #pragma unroll
    for (int tg = 0; tg < 12; ++tg) acc[tg] = 0.f;
    #pragma unroll
    for (int c = 0; c < 2; ++c) {
        int e8 = lane + (c << 6);
        uint4 xv = xr[e8];
        float x0 = flo(xv.x), x1 = fhi(xv.x);
        float x2 = flo(xv.y), x3 = fhi(xv.y);
        float x4 = flo(xv.z), x5 = fhi(xv.z);
        float x6 = flo(xv.w), x7 = fhi(xv.w);
        #pragma unroll
        for (int tg = 0; tg < 12; ++tg) {
            const float* wpt = &Wl[tg * 1024 + (e8 << 3)];
            float4 wa = *(const float4*)wpt;
            float4 wb = *(const float4*)(wpt + 4);
            acc[tg] += x0 * wa.x + x1 * wa.y + x2 * wa.z + x3 * wa.w
                     + x4 * wb.x + x5 * wb.y + x6 * wb.z + x7 * wb.w;
        }
    }
    #pragma unroll
    for (int tg = 0; tg < 12; ++tg) {
        #pragma unroll
        for (int off = 32; off > 0; off >>= 1)
            acc[tg] += __shfl_xor(acc[tg], off);
    }
    float v = 0.f;
    #pragma unroll
    for (int tg = 0; tg < 12; ++tg)
        if (lane == tg) v = acc[tg];
    if (lane < 12) Ft[row * 12 + lane] = v + bout[lane];
}

// --- Kernel 5: Viterbi per batch (1 wave). ---------------------------------
__global__ __launch_bounds__(64) void k_viterbi(const float* __restrict__ Ft,
        const float* __restrict__ trans, float* __restrict__ out) {
    int b = blockIdx.x;
    int lane = threadIdx.x;
    __shared__ unsigned char bps[512][12];
    float tr[12];
    #pragma unroll
    for (int p = 0; p < 12; ++p)
        tr[p] = (lane < 12) ? trans[lane * 12 + p] : 0.f;
    float fv = (lane == TAG_START) ? 0.f : NEGV;
    const float* fb = Ft + (size_t)b * 512 * 12;
    for (int s = 0; s < 512; ++s) {
        float m = -3.4e38f;
        int bp = 0;
        #pragma unroll
        for (int p = 0; p < 12; ++p) {
            float v = __shfl(fv, p) + tr[p];
            if (v > m) { m = v; bp = p; }
        }
        float feat = (lane < 12) ? fb[s * 12 + lane] : 0.f;
        fv = m + feat;
        if (lane < 12) bps[s][lane] = (unsigned char)bp;
    }
    float term = fv + ((lane < 12) ? trans[TAG_STOP * 12 + lane] : 0.f);
    __syncthreads();
    float best = -3.4e38f; int tag = 0;
    #pragma unroll
    for (int p = 0; p < 12; ++p) {
        float v = __shfl(term, p);
        if (v > best) { best = v; tag = p; }
    }
    if (lane == 0) {
        out[b] = best;
        int tg = tag;
        for (int s = 511; s >= 0; --s) {
            out[64 + (size_t)b * 512 + s] = (float)tg;
            tg = bps[s][tg];
        }
    }
}

extern "C" void kernel_launch(void* const* d_in, const int* in_sizes, int n_in,
                              void* d_out, int out_size, void* d_ws, size_t ws_size,
                              hipStream_t stream) {
    const int*   sent   = (const int*)  d_in[0];
    const float* emb    = (const float*)d_in[1];
    const float* W_ih_f = (const float*)d_in[2];
    const float* W_hh_f = (const float*)d_in[3];
    const float* b_f    = (const float*)d_in[4];
    const float* W_ih_b = (const float*)d_in[5];
    const float* W_hh_b = (const float*)d_in[6];
    const float* b_b    = (const float*)d_in[7];
    const float* W_out  = (const float*)d_in[8];
    const float* b_out  = (const float*)d_in[9];
    const float* trans  = (const float*)d_in[10];
    float* out = (float*)d_out;

    char* wsB = (char*)d_ws;
    size_t off = 0;
    uint32* Wq     = (uint32*)(wsB + off); off += 2097152;
    float*  s127   = (float*) (wsB + off); off += 16384;
    u16*    Wihb   = (u16*)   (wsB + off); off += 4194304;
    float*  biascat= (float*) (wsB + off); off += 16384;
    float*  Ft     = (float*) (wsB + off); off += 1572864;
    u16*    Lout   = (u16*)   (wsB + off); off += 67108864;
    size_t fixed = off;
    u16*    Gxc    = (u16*)   (wsB + off);

    int NB = 64;
    while (NB > 2 && fixed + (size_t)NB * 4194304ull > ws_size) NB >>= 1;

    k_packw<<<4096, 256, 0, stream>>>(W_ih_f, W_ih_b, b_f, b_b, Wihb, biascat);
    k_pack <<<4096, 64, 0, stream>>>(W_hh_f, W_hh_b, Wq, s127);
    for (int c = 0; c < 64; c += NB) {
        k_gemm<<<NB * 128, 256, 0, stream>>>(sent, emb, Wihb, biascat, Gxc, c);
        k_lstm<<<NB, 512, 0, stream>>>(Gxc, Wq, s127, Lout, c);
    }
    k_feats  <<<8192, 256, 0, stream>>>(Lout, W_out, b_out, Ft);
    k_viterbi<<<64, 64, 0, stream>>>(Ft, trans, out);
}